// Round 16
// baseline (91.123 us; speedup 1.0000x reference)
//
#include <hip/hip_runtime.h>

// VectorQuantizer on MI355X (gfx950) — async-pipelined MFMA argmin, 3 blocks/CU.
// R16 = r15 rhythm (self-staged E, counted vmcnt(4), lgkm-only step barriers)
// with LDS cut 74->50 KB for 24 waves/CU: 32-code chunks (16 steps) + post-loop
// scratch aliased into the dead E-dbuf region.  Empirical law across r8-r15:
// assign_time ~ 900/(waves/CU) us with no pipe saturated -> occupancy is the
// only lever that has moved this kernel.
//
// Distance core: s = ||e||^2 - 2 x.e.  E pre-scaled by 2048, f16 hi/lo split,
// PRE-SWIZZLED in ws (per-lane gld16 source, linear LDS dest).  X = f16 hi/lo
// of (-2x).  3-term MFMA (xh.eh + xh.el + xl.eh).  C-init = (||e||^2+256)*2048;
// packed key ((uint)acc << 9) | idx -> u32-min argmin, first-min tie-break.
// Near-ties (gap < 21/2048) re-solved in f64 by vq_refine (patches idx AND
// quantized rows).  Loss/hist pre-refine (error << tolerances).

typedef __attribute__((ext_vector_type(8))) _Float16 f16x8;
typedef __attribute__((ext_vector_type(4))) float f32x4;
typedef unsigned int uint;
typedef unsigned short ushort;

namespace {
constexpr int kC = 64, kH = 64, kW = 64;
constexpr int kK = 512, kD = 64;
constexpr int kHW = kH * kW;                  // 4096
constexpr int kCHW = kC * kHW;                // 262144
constexpr int kN = 32 * kHW;                  // 131072
constexpr int kQElems = 32 * kC * kHW;        // 8388608
constexpr uint kGapFP = 21u;                  // 0.0103 in 1/2048 units
}

__device__ __forceinline__ ushort hb(_Float16 h) { return __builtin_bit_cast(ushort, h); }
__device__ __forceinline__ uint umin(uint a, uint b) { return a < b ? a : b; }
__device__ __forceinline__ uint umax(uint a, uint b) { return a > b ? a : b; }

__device__ __forceinline__ void gld16(const void* g, void* l) {
  __builtin_amdgcn_global_load_lds(
      (const __attribute__((address_space(1))) uint*)g,
      (__attribute__((address_space(3))) uint*)l, 16, 0, 0);
}

// ---- kernel 0: E -> pre-swizzled f16 hi/lo (x2048) + embT + enorm + zeros ----
__global__ __launch_bounds__(64) void vq_prep(const float* __restrict__ emb,
                                              ushort* __restrict__ embPh,
                                              ushort* __restrict__ embPl,
                                              float* __restrict__ embT,
                                              float* __restrict__ enorm,
                                              uint* __restrict__ counts,
                                              uint* __restrict__ flag_count) {
  const int k = blockIdx.x * 64 + threadIdx.x;
  const float4* __restrict__ ep4 = (const float4*)(emb + k * kD);
  float ev[kD];
  uint uh[32], ul[32];
  float s = 0.f;
#pragma unroll
  for (int j = 0; j < kD / 4; ++j) {
    const float4 v = ep4[j];
    ev[4 * j] = v.x; ev[4 * j + 1] = v.y; ev[4 * j + 2] = v.z; ev[4 * j + 3] = v.w;
    s = fmaf(v.x, v.x, s); s = fmaf(v.y, v.y, s);
    s = fmaf(v.z, v.z, s); s = fmaf(v.w, v.w, s);
#pragma unroll
    for (int t = 0; t < 2; ++t) {
      const float e0 = ev[4 * j + 2 * t] * 2048.f;
      const float e1 = ev[4 * j + 2 * t + 1] * 2048.f;
      const _Float16 h0 = (_Float16)e0, h1 = (_Float16)e1;
      const _Float16 l0 = (_Float16)(e0 - (float)h0);
      const _Float16 l1 = (_Float16)(e1 - (float)h1);
      uh[2 * j + t] = (uint)hb(h0) | ((uint)hb(h1) << 16);
      ul[2 * j + t] = (uint)hb(l0) | ((uint)hb(l1) << 16);
    }
  }
  // pre-swizzled store: embP[k*128B + (cc^(k&7))*16B] = linear chunk cc
  uint4* __restrict__ ph4 = (uint4*)embPh;
  uint4* __restrict__ pl4 = (uint4*)embPl;
#pragma unroll
  for (int cc = 0; cc < 8; ++cc) {
    const int dst = k * 8 + (cc ^ (k & 7));
    ph4[dst] = uint4{uh[4 * cc], uh[4 * cc + 1], uh[4 * cc + 2], uh[4 * cc + 3]};
    pl4[dst] = uint4{ul[4 * cc], ul[4 * cc + 1], ul[4 * cc + 2], ul[4 * cc + 3]};
  }
#pragma unroll
  for (int c = 0; c < kD; ++c) embT[c * kK + k] = ev[c];
  enorm[k] = s;
  counts[k] = 0u;
  if (k == 0) *flag_count = 0u;
}

// ---- kernel 1: MFMA argmin + flags + hist + loss + QUANTIZED WRITE -----------
// Block = 512 thr = 8 waves = 128 points x all 512 codes in 16 dbuf-staged
// 32-code chunks.  Staging wave (sph=wv>>2, scs=wv&3): dims [scs*16..+16) of
// pts [sph*64..+64).  Compute wave (cph=wv>>1 in {0..3}: 32-pt quarter,
// ccs=wv&1: 16-code half); wave self-stages its own 16 chunk rows.
// C/D: col=lane&15 (code), row=(lane>>4)*4+reg (point).
__global__ __launch_bounds__(512, 4) void vq_assign(
    const float* __restrict__ in, const ushort* __restrict__ embPh,
    const ushort* __restrict__ embPl, const float* __restrict__ embT,
    const float* __restrict__ enorm, float* __restrict__ idx_out,
    float* __restrict__ outq, uint* __restrict__ counts,
    float* __restrict__ partial, uint* __restrict__ flag_count,
    uint* __restrict__ flags, uint flag_cap) {
  __shared__ __align__(16) char lds[51200];
  char* __restrict__ xbh = lds;                    // 16 KiB X hi (f16 of -2x)
  char* __restrict__ xbl = lds + 16384;            // 16 KiB X lo
  char* __restrict__ ebh = lds + 32768;            // [2][4096 B] E hi dbuf
  char* __restrict__ ebl = lds + 40960;            // [2][4096 B] E lo dbuf
  float* __restrict__ xnp = (float*)(lds + 49152); // [4][128] xnorm partials
  // aliased into the dbuf region AFTER the step loop:
  uint* __restrict__ mm1 = (uint*)(lds + 32768);   // [2][128]
  uint* __restrict__ mm2 = (uint*)(lds + 33792);   // [2][128]
  uint* __restrict__ fidx = (uint*)(lds + 34816);  // [128]
  uint* __restrict__ hist = (uint*)(lds + 35328);  // [512]

  const int tid = threadIdx.x;
  const int lane = tid & 63;
  const int wv = __builtin_amdgcn_readfirstlane(tid >> 6);
  const int sph = wv >> 2;   // staging: point-half
  const int scs = wv & 3;    // staging: dim-quarter
  const int cph = wv >> 1;   // compute: 32-pt quarter (0..3)
  const int ccs = wv & 1;    // compute: 16-code half (0..1)
  const int c = lane & 15;   // tile col (code)
  const int g = lane >> 4;   // k-chunk group 0..3

  const int blk = blockIdx.x;
  const int bb = blk >> 5;                  // batch
  const int hw0 = (blk & 31) << 7;          // 128 contiguous hw points
  const float* __restrict__ xp = in + (size_t)bb * kCHW + hw0 + sph * 64;

  // SELF-STAGE: wave (cph,ccs) stages rows [ccs*16..+16) of 32-code chunk st.
  // cph-quadruplets write identical bytes (benign).  4 gld16/wave/chunk ->
  // counted vmcnt(4) orders own reads without drains.
  auto stageE = [&](int buf, int st) {
    const size_t src = (size_t)st * 4096 + ccs * 2048;
    const int dst = buf * 4096 + ccs * 2048;
    gld16((const char*)embPh + src + lane * 16, ebh + dst);
    gld16((const char*)embPh + src + 1024 + lane * 16, ebh + dst + 1024);
    gld16((const char*)embPl + src + lane * 16, ebl + dst);
    gld16((const char*)embPl + src + 1024 + lane * 16, ebl + dst + 1024);
  };
  stageE(0, 0);   // prologue prefetch, flies under X staging

  // scaled+biased C-init per lane for the 16 chunks
  float en_pre[16];
#pragma unroll
  for (int st = 0; st < 16; ++st)
    en_pre[st] = (enorm[st * 32 + ccs * 16 + c] + 256.f) * 2048.f;

  // ---- stage X (hi/lo of -2x) + xnorm partial over this wave's 16 dims ----
  {
    const int p = lane;
    uint uh[8], ul[8];
    float xn = 0.f;
#pragma unroll
    for (int j = 0; j < 8; ++j) {
      const float f0 = xp[(size_t)(scs * 16 + 2 * j) * kHW + p];
      const float f1 = xp[(size_t)(scs * 16 + 2 * j + 1) * kHW + p];
      xn = fmaf(f0, f0, xn);
      xn = fmaf(f1, f1, xn);
      const float m0 = -2.f * f0, m1f = -2.f * f1;
      const _Float16 h0 = (_Float16)m0, h1 = (_Float16)m1f;
      const _Float16 l0 = (_Float16)(m0 - (float)h0);
      const _Float16 l1 = (_Float16)(m1f - (float)h1);
      uh[j] = (uint)hb(h0) | ((uint)hb(h1) << 16);
      ul[j] = (uint)hb(l0) | ((uint)hb(l1) << 16);
    }
    const int row = sph * 64 + p;
    const int swz = (row & 7) << 4;
    const int o0 = (row * 128 + scs * 32) ^ swz;
    const int o1 = (row * 128 + scs * 32 + 16) ^ swz;
    *(uint4*)(xbh + o0) = uint4{uh[0], uh[1], uh[2], uh[3]};
    *(uint4*)(xbh + o1) = uint4{uh[4], uh[5], uh[6], uh[7]};
    *(uint4*)(xbl + o0) = uint4{ul[0], ul[1], ul[2], ul[3]};
    *(uint4*)(xbl + o1) = uint4{ul[4], ul[5], ul[6], ul[7]};
    xnp[scs * 128 + row] = xn;
  }
  __syncthreads();   // full drain ONCE: X staged + chunk 0 landed

  uint m1[8], m2[8];
#pragma unroll
  for (int i = 0; i < 8; ++i) { m1[i] = 0xFFFFFFFFu; m2[i] = 0xFFFFFFFFu; }

#pragma unroll
  for (int st = 0; st < 16; ++st) {
    if (st < 15) stageE((st & 1) ^ 1, st + 1);   // prefetch stays in flight

    // counted wait: my own chunk-st loads landed (4 newest = chunk st+1)
    if (st < 15) {
      asm volatile("s_waitcnt vmcnt(4)" ::: "memory");
    } else {
      asm volatile("s_waitcnt vmcnt(0)" ::: "memory");
    }
    __builtin_amdgcn_sched_barrier(0);

    // B-frags: this wave's 16-code slice of the 32-code chunk (self-staged)
    const int rowb = ccs * 16 + c;
    const int swb = (rowb & 7) << 4;
    const int bbase = (st & 1) * 4096;
    const int ob0 = bbase + ((rowb * 128 + g * 16) ^ swb);
    const int ob1 = bbase + ((rowb * 128 + g * 16 + 64) ^ swb);
    const f16x8 bh0 = *(const f16x8*)(ebh + ob0);
    const f16x8 bh1 = *(const f16x8*)(ebh + ob1);
    const f16x8 bl0 = *(const f16x8*)(ebl + ob0);
    const f16x8 bl1 = *(const f16x8*)(ebl + ob1);
    const float en = en_pre[st];
    const uint kor = (uint)(st * 32 + ccs * 16 + c);
    __builtin_amdgcn_s_setprio(1);
#pragma unroll
    for (int rt = 0; rt < 2; ++rt) {
      f16x8 ah[2], al[2];
#pragma unroll
      for (int s = 0; s < 2; ++s) {
        const int row = cph * 32 + rt * 16 + c;
        const int off = (row * 128 + g * 16 + s * 64) ^ ((row & 7) << 4);
        ah[s] = *(const f16x8*)(xbh + off);
        al[s] = *(const f16x8*)(xbl + off);
      }
      f32x4 acc = {en, en, en, en};
      acc = __builtin_amdgcn_mfma_f32_16x16x32_f16(ah[0], bh0, acc, 0, 0, 0);
      acc = __builtin_amdgcn_mfma_f32_16x16x32_f16(ah[1], bh1, acc, 0, 0, 0);
      acc = __builtin_amdgcn_mfma_f32_16x16x32_f16(ah[0], bl0, acc, 0, 0, 0);
      acc = __builtin_amdgcn_mfma_f32_16x16x32_f16(ah[1], bl1, acc, 0, 0, 0);
      acc = __builtin_amdgcn_mfma_f32_16x16x32_f16(al[0], bh0, acc, 0, 0, 0);
      acc = __builtin_amdgcn_mfma_f32_16x16x32_f16(al[1], bh1, acc, 0, 0, 0);
#pragma unroll
      for (int r = 0; r < 4; ++r) {
        const uint u = ((uint)acc[r] << 9) | kor;   // fixed-point pack
        const int i = rt * 4 + r;
        const uint t = umax(m1[i], u);
        m1[i] = umin(m1[i], u);
        m2[i] = umin(m2[i], t);
      }
    }
    __builtin_amdgcn_s_setprio(0);

    // step-end rendezvous WITHOUT vmcnt drain (prefetch stays in flight)
    asm volatile("s_waitcnt lgkmcnt(0)" ::: "memory");
    __builtin_amdgcn_sched_barrier(0);
    __builtin_amdgcn_s_barrier();
  }
  // loop ended with lgkmcnt(0)+barrier -> dbuf region dead, aliases safe

  // ---- cross-col butterfly (16 c-lanes per point) ----
#pragma unroll
  for (int i = 0; i < 8; ++i) {
    uint a1 = m1[i], a2 = m2[i];
#pragma unroll
    for (int off = 1; off < 16; off <<= 1) {
      const uint o1 = __shfl_xor(a1, off, 64);
      const uint o2 = __shfl_xor(a2, off, 64);
      const uint t = umax(a1, o1);
      a1 = umin(a1, o1);
      a2 = umin(umin(a2, o2), t);
    }
    m1[i] = a1; m2[i] = a2;
  }

  if (c == 0) {
#pragma unroll
    for (int i = 0; i < 8; ++i) {
      const int rt = i >> 2, r = i & 3;
      const int p = cph * 32 + rt * 16 + g * 4 + r;
      mm1[ccs * 128 + p] = m1[i];
      mm2[ccs * 128 + p] = m2[i];
    }
  }
  hist[tid] = 0u;      // aliased region; zero after loop
  __syncthreads();

  // ---- cross-wave (2 ccs) merge + idx/flags/hist/loss ----
  if (tid < 128) {
    uint a1 = mm1[tid], a2 = mm2[tid];
    {
      const uint u1 = mm1[128 + tid], u2 = mm2[128 + tid];
      const uint t = umax(a1, u1);
      a1 = umin(a1, u1);
      a2 = umin(umin(a2, u2), t);
    }
    const uint bidx = a1 & 511u;
    fidx[tid] = bidx;
    idx_out[blk * 128 + tid] = (float)bidx;
    if (((a2 >> 9) - (a1 >> 9)) < kGapFP) {   // near-tie -> exact recheck
      const uint slot = atomicAdd(flag_count, 1u);
      if (slot < flag_cap) flags[slot] = (uint)(blk * 128 + tid);
    }
    atomicAdd(&hist[bidx], 1u);

    const float xnorm = (xnp[tid] + xnp[128 + tid]) + (xnp[256 + tid] + xnp[384 + tid]);
    float d2 = fmaf((float)(a1 >> 9), 1.f / 2048.f, -256.f) + xnorm;
#pragma unroll
    for (int off = 32; off > 0; off >>= 1) d2 += __shfl_down(d2, off, 64);
    if ((tid & 63) == 0) partial[blk * 2 + (tid >> 6)] = d2;
  }
  __syncthreads();
  if (hist[tid]) atomicAdd(&counts[tid], hist[tid]);

  // ---- fused quantized write: 128 pts x 64 c, coalesced NCHW stores ----
  {
    const int ch = tid >> 3;          // channel 0..63
    const int wq = tid & 7;           // 16-pt chunk 0..7
    const float* __restrict__ tr = embT + ch * kK;
    float* __restrict__ oq = outq + (size_t)bb * kCHW + (size_t)ch * kHW + hw0 + wq * 16;
#pragma unroll
    for (int i = 0; i < 4; ++i) {
      const int p0 = wq * 16 + i * 4;
      float4 v;
      v.x = tr[fidx[p0 + 0]];
      v.y = tr[fidx[p0 + 1]];
      v.z = tr[fidx[p0 + 2]];
      v.w = tr[fidx[p0 + 3]];
      *(float4*)(oq + i * 4) = v;
    }
  }
}

// ---- kernel 1b: exact f64 re-argmin, ONE WAVE per flagged point; patches
// both idx_out and the quantized output row.
__global__ __launch_bounds__(256) void vq_refine(const float* __restrict__ in,
                                                 const float* __restrict__ emb,
                                                 const uint* __restrict__ flag_count,
                                                 const uint* __restrict__ flags,
                                                 uint flag_cap,
                                                 float* __restrict__ idx_out,
                                                 float* __restrict__ outq) {
  uint cnt = *flag_count;
  if (cnt > flag_cap) cnt = flag_cap;
  const int lane = threadIdx.x & 63;
  const uint wave_id = blockIdx.x * 4u + (threadIdx.x >> 6);
  const uint wave_stride = gridDim.x * 4u;

  for (uint i = wave_id; i < cnt; i += wave_stride) {
    const int n = (int)flags[i];          // wave-uniform
    const int b = n >> 12;
    const int hw = n & 4095;
    const float* __restrict__ xp = in + (size_t)b * kCHW + hw;

    float xr[kD];
#pragma unroll
    for (int d = 0; d < kD; ++d) xr[d] = xp[(size_t)d * kHW];

    double best = 1e300;
    int bidx = 0;
#pragma unroll 1
    for (int kk = 0; kk < 8; ++kk) {
      const int k = lane * 8 + kk;
      const float4* __restrict__ ep4 = (const float4*)(emb + k * kD);
      double s0 = 0.0, s1 = 0.0;
#pragma unroll
      for (int j = 0; j < kD / 4; ++j) {
        const float4 e = ep4[j];
        const double d0 = (double)xr[4 * j + 0] - (double)e.x;
        const double d1 = (double)xr[4 * j + 1] - (double)e.y;
        const double d2 = (double)xr[4 * j + 2] - (double)e.z;
        const double d3 = (double)xr[4 * j + 3] - (double)e.w;
        s0 = fma(d0, d0, s0);
        s1 = fma(d1, d1, s1);
        s0 = fma(d2, d2, s0);
        s1 = fma(d3, d3, s1);
      }
      const double s = s0 + s1;
      if (s < best) { best = s; bidx = k; }  // strict < == first-min in-lane
    }
#pragma unroll
    for (int off = 32; off > 0; off >>= 1) {
      const double ob = __shfl_xor(best, off, 64);
      const int oi = __shfl_xor(bidx, off, 64);
      if (ob < best || (ob == best && oi < bidx)) { best = ob; bidx = oi; }
    }
    if (lane == 0) idx_out[n] = (float)bidx;
    // patch quantized row: lane = channel
    outq[(size_t)b * kCHW + (size_t)lane * kHW + hw] = emb[bidx * kD + lane];
  }
}

// ---- kernel 2: scalars (loss, perplexity, usage) -----------------------------
__global__ __launch_bounds__(512) void vq_finalize(const float* __restrict__ weight,
                                                   const uint* __restrict__ counts,
                                                   const float* __restrict__ partial,
                                                   float* __restrict__ out_scalars) {
  __shared__ float red[512];
  const int t = threadIdx.x;

  const float avg = (float)counts[t] / (float)kN;
  red[t] = avg * logf(avg + 1e-10f);
  __syncthreads();
#pragma unroll
  for (int off = 256; off > 0; off >>= 1) {
    if (t < off) red[t] += red[t + off];
    __syncthreads();
  }
  const float perp = expf(-red[0]);
  __syncthreads();

  // 2048 loss partials, fixed order -> deterministic
  red[t] = (partial[t] + partial[t + 512]) + (partial[t + 1024] + partial[t + 1536]);
  __syncthreads();
#pragma unroll
  for (int off = 256; off > 0; off >>= 1) {
    if (t < off) red[t] += red[t + off];
    __syncthreads();
  }
  const float loss = red[0] / (float)((long long)kN * (long long)kD);
  __syncthreads();

  red[t] = (weight[t] >= 0.01f) ? 1.f : 0.f;
  __syncthreads();
#pragma unroll
  for (int off = 256; off > 0; off >>= 1) {
    if (t < off) red[t] += red[t + off];
    __syncthreads();
  }
  if (t == 0) {
    out_scalars[0] = loss;
    out_scalars[1] = perp;
    out_scalars[2] = red[0];
  }
}

extern "C" void kernel_launch(void* const* d_in, const int* in_sizes, int n_in,
                              void* d_out, int out_size, void* d_ws, size_t ws_size,
                              hipStream_t stream) {
  const float* in = (const float*)d_in[0];
  const float* emb = (const float*)d_in[1];
  const float* weight = (const float*)d_in[2];
  float* out = (float*)d_out;

  // workspace layout (4 B units)
  float* ws_f = (float*)d_ws;
  uint* ws_u = (uint*)d_ws;
  ushort* embPh = (ushort*)d_ws;            // 64 KiB  -> u32 [0, 16384)
  ushort* embPl = embPh + kK * kD;          // 64 KiB  -> u32 [16384, 32768)
  float* embT = ws_f + 32768;               // 128 KiB -> [32768, 65536)
  float* enorm = ws_f + 65536;              // [512]
  uint* counts = ws_u + 66048;              // [512]
  float* partial = ws_f + 66560;            // [2048]
  uint* flag_count = ws_u + 68608;          // [1]
  uint* flags = ws_u + 68609;               // [flag_cap]
  const size_t ws_elems = ws_size / 4;
  const uint flag_cap =
      (ws_elems > 68609)
          ? (uint)((ws_elems - 68609 < (size_t)kN) ? ws_elems - 68609 : (size_t)kN)
          : 0u;

  float* outq = out;                    // [8388608]
  float* out_scalars = out + kQElems;   // [3]
  float* idx_out = out + kQElems + 3;   // [131072]

  vq_prep<<<8, 64, 0, stream>>>(emb, embPh, embPl, embT, enorm, counts, flag_count);
  vq_assign<<<kN / 128, 512, 0, stream>>>(in, embPh, embPl, embT, enorm, idx_out,
                                          outq, counts, partial, flag_count, flags,
                                          flag_cap);
  vq_refine<<<256, 256, 0, stream>>>(in, emb, flag_count, flags, flag_cap,
                                     idx_out, outq);
  vq_finalize<<<1, 512, 0, stream>>>(weight, counts, partial, out_scalars);
}